// Round 1
// baseline (929.373 us; speedup 1.0000x reference)
//
#include <hip/hip_runtime.h>

typedef unsigned short u16;
typedef __attribute__((ext_vector_type(8))) __bf16 bf16x8;
typedef __attribute__((ext_vector_type(4))) float f32x4;

#define LSEQ 4096
#define DMODEL 1024
#define DINNER 2048

__device__ __forceinline__ float bf2f(u16 u) {
  union { unsigned u; float f; } v; v.u = ((unsigned)u) << 16; return v.f;
}
__device__ __forceinline__ u16 f2bf(float f) {
  union { float f; unsigned u; } v; v.f = f;
  unsigned r = v.u + 0x7fffu + ((v.u >> 16) & 1u);
  return (u16)(r >> 16);
}
__device__ __forceinline__ void gload_lds16(const void* g, void* l) {
  __builtin_amdgcn_global_load_lds(
      (__attribute__((address_space(1))) void*)(unsigned long long)g,
      (__attribute__((address_space(3))) void*)(unsigned int)(unsigned long long)l,
      16, 0, 0);
}

// ---------------- LayerNorm -> bf16 ----------------
__global__ __launch_bounds__(256) void ln_kernel(const float* __restrict__ x,
                                                 const float* __restrict__ w,
                                                 const float* __restrict__ b,
                                                 u16* __restrict__ out) {
  int row = blockIdx.x;
  const float* xr = x + (size_t)row * DMODEL;
  int t = threadIdx.x;
  float4 v = ((const float4*)xr)[t];
  float s = v.x + v.y + v.z + v.w;
  float s2 = v.x * v.x + v.y * v.y + v.z * v.z + v.w * v.w;
  for (int off = 32; off; off >>= 1) {
    s += __shfl_down(s, off);
    s2 += __shfl_down(s2, off);
  }
  __shared__ float ls[4], ls2[4];
  int wid = t >> 6;
  if ((t & 63) == 0) { ls[wid] = s; ls2[wid] = s2; }
  __syncthreads();
  s = ls[0] + ls[1] + ls[2] + ls[3];
  s2 = ls2[0] + ls2[1] + ls2[2] + ls2[3];
  float mu = s * (1.f / DMODEL);
  float var = s2 * (1.f / DMODEL) - mu * mu;
  float rs = rsqrtf(var + 1e-5f);
  float4 wv = ((const float4*)w)[t];
  float4 bv = ((const float4*)b)[t];
  unsigned p0 = (unsigned)f2bf((v.x - mu) * rs * wv.x + bv.x) |
                ((unsigned)f2bf((v.y - mu) * rs * wv.y + bv.y) << 16);
  unsigned p1 = (unsigned)f2bf((v.z - mu) * rs * wv.z + bv.z) |
                ((unsigned)f2bf((v.w - mu) * rs * wv.w + bv.w) << 16);
  ((uint2*)(out + (size_t)row * DMODEL))[t] = make_uint2(p0, p1);
}

// ---------------- transpose + cast f32[K][N] -> bf16[Npad][K], zero-fill ----------------
__global__ __launch_bounds__(256) void tc_kernel(const float* __restrict__ in,
                                                 u16* __restrict__ out,
                                                 int K, int N, int Npad) {
  __shared__ float tile[32][33];
  int n0 = blockIdx.x * 32, k0 = blockIdx.y * 32;
  int tx = threadIdx.x & 31, ty = threadIdx.x >> 5;
  for (int i = ty; i < 32; i += 8) {
    int k = k0 + i, n = n0 + tx;
    tile[i][tx] = (k < K && n < N) ? in[(size_t)k * N + n] : 0.f;
  }
  __syncthreads();
  for (int i = ty; i < 32; i += 8) {
    int n = n0 + i, k = k0 + tx;
    if (n < Npad && k < K) out[(size_t)n * K + k] = f2bf(tile[tx][i]);
  }
}

// ---------------- bf16 GEMM: C[M][N] = A[M][K] * Bt[N][K]^T ----------------
template <int OUT_BF16, int ADD_RES>
__global__ __launch_bounds__(256) void gemm_bt(const u16* __restrict__ A,
                                               const u16* __restrict__ Bt,
                                               void* __restrict__ Cout,
                                               const float* __restrict__ res,
                                               int M, int N, int K) {
  __shared__ alignas(16) u16 As[128 * 32];
  __shared__ alignas(16) u16 Bs[128 * 32];
  int t = threadIdx.x;
  int w = t >> 6, ln = t & 63;
  int wr = w >> 1, wc = w & 1;
  int bm = blockIdx.y, bn = blockIdx.x;
  int lr = ln & 15, lk = (ln >> 4) * 8;
  f32x4 acc[4][4] = {};
  const u16* Abase = A + (size_t)bm * 128 * K;
  const u16* Bbase = Bt + (size_t)bn * 128 * K;
  for (int k0 = 0; k0 < K; k0 += 32) {
#pragma unroll
    for (int c = 0; c < 2; ++c) {
      int chunk = w * 2 + c;
      int ee = chunk * 512 + ln * 8;
      int row = ee >> 5, col = ee & 31;
      gload_lds16(Abase + (size_t)row * K + k0 + col, As + chunk * 512);
      gload_lds16(Bbase + (size_t)row * K + k0 + col, Bs + chunk * 512);
    }
    __syncthreads();
    bf16x8 af[4], bfr[4];
#pragma unroll
    for (int m = 0; m < 4; ++m)
      af[m] = *(const bf16x8*)(As + (wr * 64 + m * 16 + lr) * 32 + lk);
#pragma unroll
    for (int n = 0; n < 4; ++n)
      bfr[n] = *(const bf16x8*)(Bs + (wc * 64 + n * 16 + lr) * 32 + lk);
#pragma unroll
    for (int m = 0; m < 4; ++m)
#pragma unroll
      for (int n = 0; n < 4; ++n)
        acc[m][n] = __builtin_amdgcn_mfma_f32_16x16x32_bf16(af[m], bfr[n], acc[m][n], 0, 0, 0);
    __syncthreads();
  }
  int rb = bm * 128 + wr * 64 + (ln >> 4) * 4;
  int cb = bn * 128 + wc * 64 + lr;
#pragma unroll
  for (int m = 0; m < 4; ++m)
#pragma unroll
    for (int n = 0; n < 4; ++n)
#pragma unroll
      for (int r = 0; r < 4; ++r) {
        int row = rb + m * 16 + r;
        int col = cb + n * 16;
        float v = acc[m][n][r];
        if (ADD_RES) v += res[(size_t)row * N + col];
        if (OUT_BF16)
          ((u16*)Cout)[(size_t)row * N + col] = f2bf(v);
        else
          ((float*)Cout)[(size_t)row * N + col] = v;
      }
}

// ---------------- depthwise causal conv(4) + SiLU ----------------
__global__ __launch_bounds__(256) void conv_silu(const u16* __restrict__ xz,
                                                 const float* __restrict__ cw,
                                                 const float* __restrict__ cb,
                                                 u16* __restrict__ out) {
  int d = blockIdx.x * 256 + threadIdx.x;
  int l0 = blockIdx.y * 8;
  int b = blockIdx.z;
  float w0 = cw[d * 4 + 0], w1 = cw[d * 4 + 1], w2 = cw[d * 4 + 2], w3 = cw[d * 4 + 3];
  float bias = cb[d];
  const u16* xp = xz + ((size_t)b * LSEQ) * 4096 + d;
  float xv[11];
#pragma unroll
  for (int i = 0; i < 11; ++i) {
    int l = l0 - 3 + i;
    xv[i] = (l >= 0) ? bf2f(xp[(size_t)l * 4096]) : 0.f;
  }
  u16* op = out + ((size_t)b * LSEQ + l0) * DINNER + d;
#pragma unroll
  for (int i = 0; i < 8; ++i) {
    float acc = bias + w0 * xv[i] + w1 * xv[i + 1] + w2 * xv[i + 2] + w3 * xv[i + 3];
    float sv = acc / (1.f + __expf(-acc));
    op[(size_t)i * DINNER] = f2bf(sv);
  }
}

// ---------------- cast x_dbl[:, :64] -> bf16 ----------------
__global__ __launch_bounds__(256) void cast_dtlow(const float* __restrict__ xdbl,
                                                  u16* __restrict__ out) {
  int i = blockIdx.x * 256 + threadIdx.x;
  int m = i >> 6, k = i & 63;
  out[i] = f2bf(xdbl[(size_t)m * 128 + k]);
}

// ---------------- scan pass 1: per-chunk local scan (h0=0), products ----------------
__global__ __launch_bounds__(256) void scan1(const u16* __restrict__ dtpre,
                                             const float* __restrict__ bdt,
                                             const u16* __restrict__ ubf,
                                             const float* __restrict__ xdbl,
                                             const float* __restrict__ A_log,
                                             float* __restrict__ P,
                                             float* __restrict__ H) {
  int t = threadIdx.x;
  int n = t & 15, ch = t >> 4;
  int d = blockIdx.x * 16 + ch;
  int b = blockIdx.y, c = blockIdx.z;
  size_t row0 = (size_t)b * LSEQ + c * 64;
  float An = -__expf(A_log[d * 16 + n]);
  float bias = bdt[d];
  const u16* dtp = dtpre + row0 * DINNER + d;
  const u16* up = ubf + row0 * DINNER + d;
  const float* Bp = xdbl + row0 * 128 + 64 + n;
  float h = 0.f, p = 1.f;
#pragma unroll 4
  for (int i = 0; i < 64; ++i) {
    float dtr = bf2f(dtp[(size_t)i * DINNER]) + bias;
    float dt = dtr > 15.f ? dtr : __logf(1.f + __expf(dtr));
    float uu = bf2f(up[(size_t)i * DINNER]);
    float Bn = Bp[(size_t)i * 128];
    float a = __expf(dt * An);
    h = a * h + (dt * uu) * Bn;
    p *= a;
  }
  size_t idx = (size_t)c * 65536 + ((size_t)b * DINNER + d) * 16 + n;
  P[idx] = p;
  H[idx] = h;
}

// ---------------- scan pass 2: combine chunks ----------------
__global__ __launch_bounds__(256) void scan2(const float* __restrict__ P,
                                             const float* __restrict__ H,
                                             float* __restrict__ Hinit) {
  int i = blockIdx.x * 256 + threadIdx.x;
  float h = 0.f;
  for (int c = 0; c < 64; ++c) {
    Hinit[(size_t)c * 65536 + i] = h;
    h = P[(size_t)c * 65536 + i] * h + H[(size_t)c * 65536 + i];
  }
}

// ---------------- scan pass 3: replay with true h_init, fuse D-term + SiLU(z) gate ----------------
__global__ __launch_bounds__(256) void scan3(const u16* __restrict__ dtpre,
                                             const float* __restrict__ bdt,
                                             const u16* __restrict__ ubf,
                                             const float* __restrict__ xdbl,
                                             const float* __restrict__ A_log,
                                             const float* __restrict__ Dp,
                                             const u16* __restrict__ xzbf,
                                             const float* __restrict__ Hinit,
                                             u16* __restrict__ ybf) {
  int t = threadIdx.x;
  int n = t & 15, ch = t >> 4;
  int d = blockIdx.x * 16 + ch;
  int b = blockIdx.y, c = blockIdx.z;
  size_t row0 = (size_t)b * LSEQ + c * 64;
  float An = -__expf(A_log[d * 16 + n]);
  float bias = bdt[d];
  const u16* dtp = dtpre + row0 * DINNER + d;
  const u16* up = ubf + row0 * DINNER + d;
  const float* Bp = xdbl + row0 * 128 + 64 + n;
  const float* Cp = xdbl + row0 * 128 + 80 + n;
  const u16* zp = xzbf + row0 * 4096 + DINNER + d;
  u16* yp = ybf + row0 * DINNER + d;
  float h = Hinit[(size_t)c * 65536 + ((size_t)b * DINNER + d) * 16 + n];
  float Dv = Dp[d];
#pragma unroll 2
  for (int i = 0; i < 64; ++i) {
    float dtr = bf2f(dtp[(size_t)i * DINNER]) + bias;
    float dt = dtr > 15.f ? dtr : __logf(1.f + __expf(dtr));
    float uu = bf2f(up[(size_t)i * DINNER]);
    float Bn = Bp[(size_t)i * 128];
    float a = __expf(dt * An);
    h = a * h + (dt * uu) * Bn;
    float yv = h * Cp[(size_t)i * 128];
    yv += __shfl_xor(yv, 1);
    yv += __shfl_xor(yv, 2);
    yv += __shfl_xor(yv, 4);
    yv += __shfl_xor(yv, 8);
    if (n == 0) {
      float z = bf2f(zp[(size_t)i * 4096]);
      float g = z / (1.f + __expf(-z));
      yp[(size_t)i * DINNER] = f2bf((yv + uu * Dv) * g);
    }
  }
}

extern "C" void kernel_launch(void* const* d_in, const int* in_sizes, int n_in,
                              void* d_out, int out_size, void* d_ws, size_t ws_size,
                              hipStream_t stream) {
  const float* x = (const float*)d_in[0];
  const float* nw = (const float*)d_in[1];
  const float* nb = (const float*)d_in[2];
  const float* W_in = (const float*)d_in[3];
  const float* convw = (const float*)d_in[4];
  const float* convb = (const float*)d_in[5];
  const float* W_x = (const float*)d_in[6];
  const float* W_dt = (const float*)d_in[7];
  const float* b_dt = (const float*)d_in[8];
  const float* A_log = (const float*)d_in[9];
  const float* Dp = (const float*)d_in[10];
  const float* W_out = (const float*)d_in[11];
  float* out = (float*)d_out;

  char* wp = (char*)d_ws;
  auto alloc = [&](size_t bytes) {
    char* p = wp;
    wp += (bytes + 255) & ~(size_t)255;
    return p;
  };
  u16* xz_bf = (u16*)alloc((size_t)8192 * 4096 * 2);
  u16* xconv_bf = (u16*)alloc((size_t)8192 * 2048 * 2);
  u16* xn_bf = (u16*)alloc((size_t)8192 * 1024 * 2);
  float* xdbl = (float*)alloc((size_t)8192 * 128 * 4);
  u16* dtpre_bf = (u16*)alloc((size_t)8192 * 2048 * 2);
  u16* dtlow_bf = (u16*)alloc((size_t)8192 * 64 * 2);
  u16* Wint = (u16*)alloc((size_t)4096 * 1024 * 2);
  u16* Wxt = (u16*)alloc((size_t)128 * 2048 * 2);
  u16* Wdtt = (u16*)alloc((size_t)2048 * 64 * 2);
  u16* Woutt = (u16*)alloc((size_t)1024 * 2048 * 2);
  float* P = (float*)alloc((size_t)64 * 65536 * 4);
  float* H = (float*)alloc((size_t)64 * 65536 * 4);
  float* Hinit = (float*)alloc((size_t)64 * 65536 * 4);
  u16* y_bf = (u16*)P;  // overlay: P/H dead after scan2

  // weight prep (B^T bf16)
  tc_kernel<<<dim3(128, 32), 256, 0, stream>>>(W_in, Wint, 1024, 4096, 4096);
  tc_kernel<<<dim3(4, 64), 256, 0, stream>>>(W_x, Wxt, 2048, 96, 128);
  tc_kernel<<<dim3(64, 2), 256, 0, stream>>>(W_dt, Wdtt, 64, 2048, 2048);
  tc_kernel<<<dim3(32, 64), 256, 0, stream>>>(W_out, Woutt, 2048, 1024, 1024);

  ln_kernel<<<8192, 256, 0, stream>>>(x, nw, nb, xn_bf);
  gemm_bt<1, 0><<<dim3(32, 64), 256, 0, stream>>>(xn_bf, Wint, xz_bf, nullptr, 8192, 4096, 1024);
  conv_silu<<<dim3(8, 512, 2), 256, 0, stream>>>(xz_bf, convw, convb, xconv_bf);
  gemm_bt<0, 0><<<dim3(1, 64), 256, 0, stream>>>(xconv_bf, Wxt, xdbl, nullptr, 8192, 128, 2048);
  cast_dtlow<<<2048, 256, 0, stream>>>(xdbl, dtlow_bf);
  gemm_bt<1, 0><<<dim3(16, 64), 256, 0, stream>>>(dtlow_bf, Wdtt, dtpre_bf, nullptr, 8192, 2048, 64);
  scan1<<<dim3(128, 2, 64), 256, 0, stream>>>(dtpre_bf, b_dt, xconv_bf, xdbl, A_log, P, H);
  scan2<<<256, 256, 0, stream>>>(P, H, Hinit);
  scan3<<<dim3(128, 2, 64), 256, 0, stream>>>(dtpre_bf, b_dt, xconv_bf, xdbl, A_log, Dp, xz_bf,
                                              Hinit, y_bf);
  gemm_bt<0, 1><<<dim3(8, 64), 256, 0, stream>>>(y_bf, Woutt, out, x, 8192, 1024, 2048);
}

// Round 2
// 423.548 us; speedup vs baseline: 2.1943x; 2.1943x over previous
//
#include <hip/hip_runtime.h>

typedef unsigned short u16;
typedef __attribute__((ext_vector_type(8))) __bf16 bf16x8;
typedef __attribute__((ext_vector_type(4))) float f32x4;

#define LSEQ 4096
#define DMODEL 1024
#define DINNER 2048

__device__ __forceinline__ float bf2f(u16 u) {
  union { unsigned u; float f; } v; v.u = ((unsigned)u) << 16; return v.f;
}
__device__ __forceinline__ u16 f2bf(float f) {
  union { float f; unsigned u; } v; v.f = f;
  unsigned r = v.u + 0x7fffu + ((v.u >> 16) & 1u);
  return (u16)(r >> 16);
}
__device__ __forceinline__ void gload_lds16(const void* g, void* l) {
  __builtin_amdgcn_global_load_lds(
      (__attribute__((address_space(1))) void*)(unsigned long long)g,
      (__attribute__((address_space(3))) void*)(unsigned int)(unsigned long long)l,
      16, 0, 0);
}
__device__ __forceinline__ float sigmoidf_(float v) { return 1.f / (1.f + __expf(-v)); }

// ---------------- LayerNorm -> bf16 ----------------
__global__ __launch_bounds__(256) void ln_kernel(const float* __restrict__ x,
                                                 const float* __restrict__ w,
                                                 const float* __restrict__ b,
                                                 u16* __restrict__ out) {
  int row = blockIdx.x;
  const float* xr = x + (size_t)row * DMODEL;
  int t = threadIdx.x;
  float4 v = ((const float4*)xr)[t];
  float s = v.x + v.y + v.z + v.w;
  float s2 = v.x * v.x + v.y * v.y + v.z * v.z + v.w * v.w;
  for (int off = 32; off; off >>= 1) {
    s += __shfl_down(s, off);
    s2 += __shfl_down(s2, off);
  }
  __shared__ float ls[4], ls2[4];
  int wid = t >> 6;
  if ((t & 63) == 0) { ls[wid] = s; ls2[wid] = s2; }
  __syncthreads();
  s = ls[0] + ls[1] + ls[2] + ls[3];
  s2 = ls2[0] + ls2[1] + ls2[2] + ls2[3];
  float mu = s * (1.f / DMODEL);
  float var = s2 * (1.f / DMODEL) - mu * mu;
  float rs = rsqrtf(var + 1e-5f);
  float4 wv = ((const float4*)w)[t];
  float4 bv = ((const float4*)b)[t];
  unsigned p0 = (unsigned)f2bf((v.x - mu) * rs * wv.x + bv.x) |
                ((unsigned)f2bf((v.y - mu) * rs * wv.y + bv.y) << 16);
  unsigned p1 = (unsigned)f2bf((v.z - mu) * rs * wv.z + bv.z) |
                ((unsigned)f2bf((v.w - mu) * rs * wv.w + bv.w) << 16);
  ((uint2*)(out + (size_t)row * DMODEL))[t] = make_uint2(p0, p1);
}

// ---------------- transpose + cast f32[K][N] -> bf16[Npad][K], zero-fill ----------------
__global__ __launch_bounds__(256) void tc_kernel(const float* __restrict__ in,
                                                 u16* __restrict__ out,
                                                 int K, int N, int Npad) {
  __shared__ float tile[32][33];
  int n0 = blockIdx.x * 32, k0 = blockIdx.y * 32;
  int tx = threadIdx.x & 31, ty = threadIdx.x >> 5;
  for (int i = ty; i < 32; i += 8) {
    int k = k0 + i, n = n0 + tx;
    tile[i][tx] = (k < K && n < N) ? in[(size_t)k * N + n] : 0.f;
  }
  __syncthreads();
  for (int i = ty; i < 32; i += 8) {
    int n = n0 + i, k = k0 + tx;
    if (n < Npad && k < K) out[(size_t)n * K + k] = f2bf(tile[tx][i]);
  }
}

// ---------------- bf16 GEMM: C[M][N] = A[M][K] * Bt[N][K]^T ----------------
// EPI: 0 none, 1 add f32 residual (aux), 2 silu for col>=cthresh,
//      3 softplus(v + aux[col]), 4 f32 out + bf16 side-write of cols<64 to aux2
template <int OUT_BF16, int EPI>
__global__ __launch_bounds__(256) void gemm_bt(const u16* __restrict__ A,
                                               const u16* __restrict__ Bt,
                                               void* __restrict__ Cout,
                                               const float* __restrict__ aux,
                                               u16* __restrict__ aux2,
                                               int M, int N, int K, int cthresh) {
  __shared__ alignas(16) u16 As[128 * 32];
  __shared__ alignas(16) u16 Bs[128 * 32];
  int t = threadIdx.x;
  int w = t >> 6, ln = t & 63;
  int wr = w >> 1, wc = w & 1;
  int bm = blockIdx.y, bn = blockIdx.x;
  int lr = ln & 15, lk = (ln >> 4) * 8;
  f32x4 acc[4][4] = {};
  const u16* Abase = A + (size_t)bm * 128 * K;
  const u16* Bbase = Bt + (size_t)bn * 128 * K;
  for (int k0 = 0; k0 < K; k0 += 32) {
#pragma unroll
    for (int c = 0; c < 2; ++c) {
      int chunk = w * 2 + c;
      int ee = chunk * 512 + ln * 8;
      int row = ee >> 5, col = ee & 31;
      gload_lds16(Abase + (size_t)row * K + k0 + col, As + chunk * 512);
      gload_lds16(Bbase + (size_t)row * K + k0 + col, Bs + chunk * 512);
    }
    __syncthreads();
    bf16x8 af[4], bfr[4];
#pragma unroll
    for (int m = 0; m < 4; ++m)
      af[m] = *(const bf16x8*)(As + (wr * 64 + m * 16 + lr) * 32 + lk);
#pragma unroll
    for (int n = 0; n < 4; ++n)
      bfr[n] = *(const bf16x8*)(Bs + (wc * 64 + n * 16 + lr) * 32 + lk);
#pragma unroll
    for (int m = 0; m < 4; ++m)
#pragma unroll
      for (int n = 0; n < 4; ++n)
        acc[m][n] = __builtin_amdgcn_mfma_f32_16x16x32_bf16(af[m], bfr[n], acc[m][n], 0, 0, 0);
    __syncthreads();
  }
  int rb = bm * 128 + wr * 64 + (ln >> 4) * 4;
  int cb = bn * 128 + wc * 64 + lr;
#pragma unroll
  for (int m = 0; m < 4; ++m)
#pragma unroll
    for (int n = 0; n < 4; ++n)
#pragma unroll
      for (int r = 0; r < 4; ++r) {
        int row = rb + m * 16 + r;
        int col = cb + n * 16;
        float v = acc[m][n][r];
        if (EPI == 1) v += aux[(size_t)row * N + col];
        if (EPI == 2 && col >= cthresh) v = v * sigmoidf_(v);
        if (EPI == 3) {
          float dtr = v + aux[col];
          v = dtr > 15.f ? dtr : __logf(1.f + __expf(dtr));
        }
        if (OUT_BF16)
          ((u16*)Cout)[(size_t)row * N + col] = f2bf(v);
        else
          ((float*)Cout)[(size_t)row * N + col] = v;
        if (EPI == 4 && col < 64) aux2[(size_t)row * 64 + col] = f2bf(v);
      }
}

// ---------------- depthwise causal conv(4) + SiLU ----------------
__global__ __launch_bounds__(256) void conv_silu(const u16* __restrict__ xz,
                                                 const float* __restrict__ cw,
                                                 const float* __restrict__ cb,
                                                 u16* __restrict__ out) {
  int d = blockIdx.x * 256 + threadIdx.x;
  int l0 = blockIdx.y * 8;
  int b = blockIdx.z;
  float w0 = cw[d * 4 + 0], w1 = cw[d * 4 + 1], w2 = cw[d * 4 + 2], w3 = cw[d * 4 + 3];
  float bias = cb[d];
  const u16* xp = xz + ((size_t)b * LSEQ) * 4096 + d;
  float xv[11];
#pragma unroll
  for (int i = 0; i < 11; ++i) {
    int l = l0 - 3 + i;
    xv[i] = (l >= 0) ? bf2f(xp[(size_t)l * 4096]) : 0.f;
  }
  u16* op = out + ((size_t)b * LSEQ + l0) * DINNER + d;
#pragma unroll
  for (int i = 0; i < 8; ++i) {
    float acc = bias + w0 * xv[i] + w1 * xv[i + 1] + w2 * xv[i + 2] + w3 * xv[i + 3];
    float sv = acc * sigmoidf_(acc);
    op[(size_t)i * DINNER] = f2bf(sv);
  }
}

// ---------------- scan pass 1: per-chunk local scan; 1 lane = 1 channel, 16 states in regs ----
__global__ __launch_bounds__(256) void scan1(const u16* __restrict__ dtbf,
                                             const u16* __restrict__ ubf,
                                             const float* __restrict__ xdbl,
                                             const float* __restrict__ A_log,
                                             float* __restrict__ P,
                                             float* __restrict__ H) {
  int d = blockIdx.x * 256 + threadIdx.x;
  int b = blockIdx.y, c = blockIdx.z;
  size_t row0 = (size_t)b * LSEQ + c * 64;
  float An[16];
  {
    const float4* A4 = (const float4*)(A_log + (size_t)d * 16);
#pragma unroll
    for (int q = 0; q < 4; ++q) {
      float4 a = A4[q];
      An[q * 4 + 0] = -__expf(a.x);
      An[q * 4 + 1] = -__expf(a.y);
      An[q * 4 + 2] = -__expf(a.z);
      An[q * 4 + 3] = -__expf(a.w);
    }
  }
  const u16* dtp = dtbf + row0 * DINNER + d;
  const u16* up = ubf + row0 * DINNER + d;
  const float* Bp = xdbl + row0 * 128 + 64;
  float h[16], p[16];
#pragma unroll
  for (int n = 0; n < 16; ++n) { h[n] = 0.f; p[n] = 1.f; }
#pragma unroll 2
  for (int i = 0; i < 64; ++i) {
    float dt = bf2f(dtp[(size_t)i * DINNER]);
    float uu = bf2f(up[(size_t)i * DINNER]);
    float dtu = dt * uu;
    const float4* B4 = (const float4*)(Bp + (size_t)i * 128);
    float4 b0 = B4[0], b1 = B4[1], b2 = B4[2], b3 = B4[3];
    float Bf[16] = {b0.x, b0.y, b0.z, b0.w, b1.x, b1.y, b1.z, b1.w,
                    b2.x, b2.y, b2.z, b2.w, b3.x, b3.y, b3.z, b3.w};
#pragma unroll
    for (int n = 0; n < 16; ++n) {
      float a = __expf(dt * An[n]);
      p[n] *= a;
      h[n] = a * h[n] + dtu * Bf[n];
    }
  }
  size_t idx = (size_t)c * 65536 + ((size_t)b * DINNER + d) * 16;
  float4* P4 = (float4*)(P + idx);
  float4* H4 = (float4*)(H + idx);
#pragma unroll
  for (int q = 0; q < 4; ++q) {
    P4[q] = make_float4(p[q * 4], p[q * 4 + 1], p[q * 4 + 2], p[q * 4 + 3]);
    H4[q] = make_float4(h[q * 4], h[q * 4 + 1], h[q * 4 + 2], h[q * 4 + 3]);
  }
}

// ---------------- scan pass 2: combine chunks ----------------
__global__ __launch_bounds__(256) void scan2(const float* __restrict__ P,
                                             const float* __restrict__ H,
                                             float* __restrict__ Hinit) {
  int i = blockIdx.x * 256 + threadIdx.x;
  float h = 0.f;
  for (int c = 0; c < 64; ++c) {
    Hinit[(size_t)c * 65536 + i] = h;
    h = P[(size_t)c * 65536 + i] * h + H[(size_t)c * 65536 + i];
  }
}

// ---------------- scan pass 3: replay with true h_init; fused D-term + precomputed gate ----
__global__ __launch_bounds__(256) void scan3(const u16* __restrict__ dtbf,
                                             const u16* __restrict__ ubf,
                                             const float* __restrict__ xdbl,
                                             const float* __restrict__ A_log,
                                             const float* __restrict__ Dp,
                                             const u16* __restrict__ xzbf,
                                             const float* __restrict__ Hinit,
                                             u16* __restrict__ ybf) {
  int d = blockIdx.x * 256 + threadIdx.x;
  int b = blockIdx.y, c = blockIdx.z;
  size_t row0 = (size_t)b * LSEQ + c * 64;
  float An[16];
  {
    const float4* A4 = (const float4*)(A_log + (size_t)d * 16);
#pragma unroll
    for (int q = 0; q < 4; ++q) {
      float4 a = A4[q];
      An[q * 4 + 0] = -__expf(a.x);
      An[q * 4 + 1] = -__expf(a.y);
      An[q * 4 + 2] = -__expf(a.z);
      An[q * 4 + 3] = -__expf(a.w);
    }
  }
  const u16* dtp = dtbf + row0 * DINNER + d;
  const u16* up = ubf + row0 * DINNER + d;
  const float* Bp = xdbl + row0 * 128 + 64;
  const float* Cp = xdbl + row0 * 128 + 80;
  const u16* gp = xzbf + row0 * 4096 + DINNER + d;  // silu(z), precomputed in GEMM1
  u16* yp = ybf + row0 * DINNER + d;
  float Dv = Dp[d];
  float h[16];
  {
    const float4* Hi4 = (const float4*)(Hinit + (size_t)c * 65536 + ((size_t)b * DINNER + d) * 16);
#pragma unroll
    for (int q = 0; q < 4; ++q) {
      float4 hv = Hi4[q];
      h[q * 4 + 0] = hv.x; h[q * 4 + 1] = hv.y; h[q * 4 + 2] = hv.z; h[q * 4 + 3] = hv.w;
    }
  }
#pragma unroll 2
  for (int i = 0; i < 64; ++i) {
    float dt = bf2f(dtp[(size_t)i * DINNER]);
    float uu = bf2f(up[(size_t)i * DINNER]);
    float dtu = dt * uu;
    const float4* B4 = (const float4*)(Bp + (size_t)i * 128);
    float4 b0 = B4[0], b1 = B4[1], b2 = B4[2], b3 = B4[3];
    float Bf[16] = {b0.x, b0.y, b0.z, b0.w, b1.x, b1.y, b1.z, b1.w,
                    b2.x, b2.y, b2.z, b2.w, b3.x, b3.y, b3.z, b3.w};
    const float4* C4 = (const float4*)(Cp + (size_t)i * 128);
    float4 c0 = C4[0], c1 = C4[1], c2 = C4[2], c3 = C4[3];
    float Cf[16] = {c0.x, c0.y, c0.z, c0.w, c1.x, c1.y, c1.z, c1.w,
                    c2.x, c2.y, c2.z, c2.w, c3.x, c3.y, c3.z, c3.w};
    float y = 0.f;
#pragma unroll
    for (int n = 0; n < 16; ++n) {
      float a = __expf(dt * An[n]);
      h[n] = a * h[n] + dtu * Bf[n];
      y += h[n] * Cf[n];
    }
    float g = bf2f(gp[(size_t)i * 4096]);
    yp[(size_t)i * DINNER] = f2bf((y + uu * Dv) * g);
  }
}

extern "C" void kernel_launch(void* const* d_in, const int* in_sizes, int n_in,
                              void* d_out, int out_size, void* d_ws, size_t ws_size,
                              hipStream_t stream) {
  const float* x = (const float*)d_in[0];
  const float* nw = (const float*)d_in[1];
  const float* nb = (const float*)d_in[2];
  const float* W_in = (const float*)d_in[3];
  const float* convw = (const float*)d_in[4];
  const float* convb = (const float*)d_in[5];
  const float* W_x = (const float*)d_in[6];
  const float* W_dt = (const float*)d_in[7];
  const float* b_dt = (const float*)d_in[8];
  const float* A_log = (const float*)d_in[9];
  const float* Dp = (const float*)d_in[10];
  const float* W_out = (const float*)d_in[11];
  float* out = (float*)d_out;

  char* wp = (char*)d_ws;
  auto alloc = [&](size_t bytes) {
    char* p = wp;
    wp += (bytes + 255) & ~(size_t)255;
    return p;
  };
  u16* xz_bf = (u16*)alloc((size_t)8192 * 4096 * 2);     // x half raw, z half silu'd
  u16* xconv_bf = (u16*)alloc((size_t)8192 * 2048 * 2);  // u
  u16* xn_bf = (u16*)alloc((size_t)8192 * 1024 * 2);
  float* xdbl = (float*)alloc((size_t)8192 * 128 * 4);
  u16* dt_bf = (u16*)alloc((size_t)8192 * 2048 * 2);     // softplus'd dt
  u16* dtlow_bf = (u16*)alloc((size_t)8192 * 64 * 2);
  u16* Wint = (u16*)alloc((size_t)4096 * 1024 * 2);
  u16* Wxt = (u16*)alloc((size_t)128 * 2048 * 2);
  u16* Wdtt = (u16*)alloc((size_t)2048 * 64 * 2);
  u16* Woutt = (u16*)alloc((size_t)1024 * 2048 * 2);
  float* P = (float*)alloc((size_t)64 * 65536 * 4);
  float* H = (float*)alloc((size_t)64 * 65536 * 4);
  float* Hinit = (float*)alloc((size_t)64 * 65536 * 4);
  u16* y_bf = (u16*)P;  // overlay: P+H dead after scan2, y needs 33.5MB = |P|+|H|

  // weight prep (B^T bf16)
  tc_kernel<<<dim3(128, 32), 256, 0, stream>>>(W_in, Wint, 1024, 4096, 4096);
  tc_kernel<<<dim3(4, 64), 256, 0, stream>>>(W_x, Wxt, 2048, 96, 128);
  tc_kernel<<<dim3(64, 2), 256, 0, stream>>>(W_dt, Wdtt, 64, 2048, 2048);
  tc_kernel<<<dim3(32, 64), 256, 0, stream>>>(W_out, Woutt, 2048, 1024, 1024);

  ln_kernel<<<8192, 256, 0, stream>>>(x, nw, nb, xn_bf);
  // xz = xn @ W_in, z-half gets silu applied in epilogue
  gemm_bt<1, 2><<<dim3(32, 64), 256, 0, stream>>>(xn_bf, Wint, xz_bf, nullptr, nullptr,
                                                  8192, 4096, 1024, 2048);
  conv_silu<<<dim3(8, 512, 2), 256, 0, stream>>>(xz_bf, convw, convb, xconv_bf);
  // x_dbl = x_conv @ W_x (f32) + bf16 side-copy of dt_low cols
  gemm_bt<0, 4><<<dim3(1, 64), 256, 0, stream>>>(xconv_bf, Wxt, xdbl, nullptr, dtlow_bf,
                                                 8192, 128, 2048, 0);
  // dt = softplus(dt_low @ W_dt + b_dt)
  gemm_bt<1, 3><<<dim3(16, 64), 256, 0, stream>>>(dtlow_bf, Wdtt, dt_bf, b_dt, nullptr,
                                                  8192, 2048, 64, 0);
  scan1<<<dim3(8, 2, 64), 256, 0, stream>>>(dt_bf, xconv_bf, xdbl, A_log, P, H);
  scan2<<<256, 256, 0, stream>>>(P, H, Hinit);
  scan3<<<dim3(8, 2, 64), 256, 0, stream>>>(dt_bf, xconv_bf, xdbl, A_log, Dp, xz_bf,
                                            Hinit, y_bf);
  // out = residual + y @ W_out
  gemm_bt<0, 1><<<dim3(8, 64), 256, 0, stream>>>(y_bf, Woutt, out, x, nullptr,
                                                 8192, 1024, 2048, 0);
}

// Round 3
// 362.689 us; speedup vs baseline: 2.5625x; 1.1678x over previous
//
#include <hip/hip_runtime.h>

typedef unsigned short u16;
typedef __attribute__((ext_vector_type(8))) __bf16 bf16x8;
typedef __attribute__((ext_vector_type(4))) float f32x4;

#define LSEQ 4096
#define DMODEL 1024
#define DINNER 2048

__device__ __forceinline__ float bf2f(u16 u) {
  union { unsigned u; float f; } v; v.u = ((unsigned)u) << 16; return v.f;
}
__device__ __forceinline__ u16 f2bf(float f) {
  union { float f; unsigned u; } v; v.f = f;
  unsigned r = v.u + 0x7fffu + ((v.u >> 16) & 1u);
  return (u16)(r >> 16);
}
__device__ __forceinline__ void gload_lds16(const void* g, void* l) {
  __builtin_amdgcn_global_load_lds(
      (__attribute__((address_space(1))) void*)(unsigned long long)g,
      (__attribute__((address_space(3))) void*)(unsigned int)(unsigned long long)l,
      16, 0, 0);
}
__device__ __forceinline__ float sigmoidf_(float v) { return 1.f / (1.f + __expf(-v)); }

// ---------------- LayerNorm -> bf16 ----------------
__global__ __launch_bounds__(256) void ln_kernel(const float* __restrict__ x,
                                                 const float* __restrict__ w,
                                                 const float* __restrict__ b,
                                                 u16* __restrict__ out) {
  int row = blockIdx.x;
  const float* xr = x + (size_t)row * DMODEL;
  int t = threadIdx.x;
  float4 v = ((const float4*)xr)[t];
  float s = v.x + v.y + v.z + v.w;
  float s2 = v.x * v.x + v.y * v.y + v.z * v.z + v.w * v.w;
  for (int off = 32; off; off >>= 1) {
    s += __shfl_down(s, off);
    s2 += __shfl_down(s2, off);
  }
  __shared__ float ls[4], ls2[4];
  int wid = t >> 6;
  if ((t & 63) == 0) { ls[wid] = s; ls2[wid] = s2; }
  __syncthreads();
  s = ls[0] + ls[1] + ls[2] + ls[3];
  s2 = ls2[0] + ls2[1] + ls2[2] + ls2[3];
  float mu = s * (1.f / DMODEL);
  float var = s2 * (1.f / DMODEL) - mu * mu;
  float rs = rsqrtf(var + 1e-5f);
  float4 wv = ((const float4*)w)[t];
  float4 bv = ((const float4*)b)[t];
  unsigned p0 = (unsigned)f2bf((v.x - mu) * rs * wv.x + bv.x) |
                ((unsigned)f2bf((v.y - mu) * rs * wv.y + bv.y) << 16);
  unsigned p1 = (unsigned)f2bf((v.z - mu) * rs * wv.z + bv.z) |
                ((unsigned)f2bf((v.w - mu) * rs * wv.w + bv.w) << 16);
  ((uint2*)(out + (size_t)row * DMODEL))[t] = make_uint2(p0, p1);
}

// ---------------- transpose + cast f32[K][N] -> bf16[Npad][K], zero-fill ----------------
__global__ __launch_bounds__(256) void tc_kernel(const float* __restrict__ in,
                                                 u16* __restrict__ out,
                                                 int K, int N, int Npad) {
  __shared__ float tile[32][33];
  int n0 = blockIdx.x * 32, k0 = blockIdx.y * 32;
  int tx = threadIdx.x & 31, ty = threadIdx.x >> 5;
  for (int i = ty; i < 32; i += 8) {
    int k = k0 + i, n = n0 + tx;
    tile[i][tx] = (k < K && n < N) ? in[(size_t)k * N + n] : 0.f;
  }
  __syncthreads();
  for (int i = ty; i < 32; i += 8) {
    int n = n0 + i, k = k0 + tx;
    if (n < Npad && k < K) out[(size_t)n * K + k] = f2bf(tile[tx][i]);
  }
}

// ---------------- bf16 GEMM: C[M][N] = A[M][K_eff] * Bt[N][K_eff]^T, row stride ld ----------
// EPI: 0 none, 1 add f32 residual (aux), 2 silu for col>=cthresh, 3 softplus(v + aux[col])
// SPLITK: blockIdx.z selects K-chunk of size K; f32 partial written at z*M*N offset
template <int OUT_BF16, int EPI, int SPLITK>
__global__ __launch_bounds__(256) void gemm_bt(const u16* __restrict__ A,
                                               const u16* __restrict__ Bt,
                                               void* __restrict__ Cout,
                                               const float* __restrict__ aux,
                                               int M, int N, int K, int ld, int cthresh) {
  __shared__ alignas(16) u16 As[128 * 32];
  __shared__ alignas(16) u16 Bs[128 * 32];
  int t = threadIdx.x;
  int w = t >> 6, ln = t & 63;
  int wr = w >> 1, wc = w & 1;
  int bm = blockIdx.y, bn = blockIdx.x;
  int lr = ln & 15, lk = (ln >> 4) * 8;
  f32x4 acc[4][4] = {};
  int kz = SPLITK ? blockIdx.z * K : 0;
  const u16* Abase = A + (size_t)bm * 128 * ld + kz;
  const u16* Bbase = Bt + (size_t)bn * 128 * ld + kz;
  for (int k0 = 0; k0 < K; k0 += 32) {
#pragma unroll
    for (int c = 0; c < 2; ++c) {
      int chunk = w * 2 + c;
      int ee = chunk * 512 + ln * 8;
      int row = ee >> 5, col = ee & 31;
      gload_lds16(Abase + (size_t)row * ld + k0 + col, As + chunk * 512);
      gload_lds16(Bbase + (size_t)row * ld + k0 + col, Bs + chunk * 512);
    }
    __syncthreads();
    bf16x8 af[4], bfr[4];
#pragma unroll
    for (int m = 0; m < 4; ++m)
      af[m] = *(const bf16x8*)(As + (wr * 64 + m * 16 + lr) * 32 + lk);
#pragma unroll
    for (int n = 0; n < 4; ++n)
      bfr[n] = *(const bf16x8*)(Bs + (wc * 64 + n * 16 + lr) * 32 + lk);
#pragma unroll
    for (int m = 0; m < 4; ++m)
#pragma unroll
      for (int n = 0; n < 4; ++n)
        acc[m][n] = __builtin_amdgcn_mfma_f32_16x16x32_bf16(af[m], bfr[n], acc[m][n], 0, 0, 0);
    __syncthreads();
  }
  int rb = bm * 128 + wr * 64 + (ln >> 4) * 4;
  int cb = bn * 128 + wc * 64 + lr;
  float* Cpart = SPLITK ? ((float*)Cout + (size_t)blockIdx.z * M * N) : (float*)Cout;
#pragma unroll
  for (int m = 0; m < 4; ++m)
#pragma unroll
    for (int n = 0; n < 4; ++n)
#pragma unroll
      for (int r = 0; r < 4; ++r) {
        int row = rb + m * 16 + r;
        int col = cb + n * 16;
        float v = acc[m][n][r];
        if (EPI == 1) v += aux[(size_t)row * N + col];
        if (EPI == 2 && col >= cthresh) v = v * sigmoidf_(v);
        if (EPI == 3) {
          float dtr = v + aux[col];
          v = dtr > 15.f ? dtr : __logf(1.f + __expf(dtr));
        }
        if (OUT_BF16)
          ((u16*)Cpart)[(size_t)row * N + col] = f2bf(v);
        else
          Cpart[(size_t)row * N + col] = v;
      }
}

// ---------------- reduce split-K partials -> xdbl f32, side-write dt_low bf16 ----------------
__global__ __launch_bounds__(256) void reduce_xdbl(const float* __restrict__ part,
                                                   float* __restrict__ xdbl,
                                                   u16* __restrict__ dtlow) {
  int i = blockIdx.x * 256 + threadIdx.x;  // over 8192*128
  float s = 0.f;
#pragma unroll
  for (int z = 0; z < 8; ++z) s += part[(size_t)z * (8192 * 128) + i];
  xdbl[i] = s;
  int col = i & 127;
  if (col < 64) dtlow[(size_t)(i >> 7) * 64 + col] = f2bf(s);
}

// ---------------- depthwise causal conv(4) + SiLU ----------------
__global__ __launch_bounds__(256) void conv_silu(const u16* __restrict__ xz,
                                                 const float* __restrict__ cw,
                                                 const float* __restrict__ cb,
                                                 u16* __restrict__ out) {
  int d = blockIdx.x * 256 + threadIdx.x;
  int l0 = blockIdx.y * 8;
  int b = blockIdx.z;
  float w0 = cw[d * 4 + 0], w1 = cw[d * 4 + 1], w2 = cw[d * 4 + 2], w3 = cw[d * 4 + 3];
  float bias = cb[d];
  const u16* xp = xz + ((size_t)b * LSEQ) * 4096 + d;
  float xv[11];
#pragma unroll
  for (int i = 0; i < 11; ++i) {
    int l = l0 - 3 + i;
    xv[i] = (l >= 0) ? bf2f(xp[(size_t)l * 4096]) : 0.f;
  }
  u16* op = out + ((size_t)b * LSEQ + l0) * DINNER + d;
#pragma unroll
  for (int i = 0; i < 8; ++i) {
    float acc = bias + w0 * xv[i] + w1 * xv[i + 1] + w2 * xv[i + 2] + w3 * xv[i + 3];
    float sv = acc * sigmoidf_(acc);
    op[(size_t)i * DINNER] = f2bf(sv);
  }
}

// ---- compute a[16] = exp(dt*An[n]); fast path when An = -(n+1) (uniform branch) ----
__device__ __forceinline__ void compute_a(float dt, const float* An, bool fast, float* av) {
  if (fast) {
    float q = __expf(-dt);
    float q2 = q * q, q4 = q2 * q2;
    av[0] = q; av[1] = q2; av[2] = q2 * q; av[3] = q4;
#pragma unroll
    for (int n = 4; n < 16; ++n) av[n] = av[n - 4] * q4;
  } else {
#pragma unroll
    for (int n = 0; n < 16; ++n) av[n] = __expf(dt * An[n]);
  }
}

// ---------------- scan pass 1: per-chunk local scan; 1 lane = 1 channel ----------------
__global__ __launch_bounds__(256) void scan1(const u16* __restrict__ dtbf,
                                             const u16* __restrict__ ubf,
                                             const float* __restrict__ xdbl,
                                             const float* __restrict__ A_log,
                                             float* __restrict__ P,
                                             float* __restrict__ H) {
  int d = blockIdx.x * 256 + threadIdx.x;
  int b = blockIdx.y, c = blockIdx.z;
  size_t row0 = (size_t)b * LSEQ + c * 64;
  float An[16];
  bool fast = true;
  {
    const float4* A4 = (const float4*)(A_log + (size_t)d * 16);
#pragma unroll
    for (int q = 0; q < 4; ++q) {
      float4 a = A4[q];
      An[q * 4 + 0] = -__expf(a.x);
      An[q * 4 + 1] = -__expf(a.y);
      An[q * 4 + 2] = -__expf(a.z);
      An[q * 4 + 3] = -__expf(a.w);
    }
#pragma unroll
    for (int n = 0; n < 16; ++n)
      fast = fast && (__builtin_fabsf(An[n] + (float)(n + 1)) < 1e-3f * (n + 1));
  }
  const u16* dtp = dtbf + row0 * DINNER + d;
  const u16* up = ubf + row0 * DINNER + d;
  const float* Bp = xdbl + row0 * 128 + 64;
  float h[16];
#pragma unroll
  for (int n = 0; n < 16; ++n) h[n] = 0.f;
  float sdt = 0.f;
#pragma unroll 2
  for (int i = 0; i < 64; ++i) {
    float dt = bf2f(dtp[(size_t)i * DINNER]);
    float uu = bf2f(up[(size_t)i * DINNER]);
    float dtu = dt * uu;
    sdt += dt;
    const float4* B4 = (const float4*)(Bp + (size_t)i * 128);
    float4 b0 = B4[0], b1 = B4[1], b2 = B4[2], b3 = B4[3];
    float Bf[16] = {b0.x, b0.y, b0.z, b0.w, b1.x, b1.y, b1.z, b1.w,
                    b2.x, b2.y, b2.z, b2.w, b3.x, b3.y, b3.z, b3.w};
    float av[16];
    compute_a(dt, An, fast, av);
#pragma unroll
    for (int n = 0; n < 16; ++n) h[n] = av[n] * h[n] + dtu * Bf[n];
  }
  size_t idx = (size_t)c * 65536 + ((size_t)b * DINNER + d) * 16;
  float4* P4 = (float4*)(P + idx);
  float4* H4 = (float4*)(H + idx);
#pragma unroll
  for (int q = 0; q < 4; ++q) {
    // P[n] = prod_i exp(dt_i*An) = exp(An * sum dt)  (An time-constant)
    P4[q] = make_float4(__expf(An[q * 4 + 0] * sdt), __expf(An[q * 4 + 1] * sdt),
                        __expf(An[q * 4 + 2] * sdt), __expf(An[q * 4 + 3] * sdt));
    H4[q] = make_float4(h[q * 4], h[q * 4 + 1], h[q * 4 + 2], h[q * 4 + 3]);
  }
}

// ---------------- scan pass 2: combine chunks ----------------
__global__ __launch_bounds__(256) void scan2(const float* __restrict__ P,
                                             const float* __restrict__ H,
                                             float* __restrict__ Hinit) {
  int i = blockIdx.x * 256 + threadIdx.x;
  float h = 0.f;
  for (int c = 0; c < 64; ++c) {
    Hinit[(size_t)c * 65536 + i] = h;
    h = P[(size_t)c * 65536 + i] * h + H[(size_t)c * 65536 + i];
  }
}

// ---------------- scan pass 3: replay with true h_init; fused D-term + precomputed gate ----
__global__ __launch_bounds__(256) void scan3(const u16* __restrict__ dtbf,
                                             const u16* __restrict__ ubf,
                                             const float* __restrict__ xdbl,
                                             const float* __restrict__ A_log,
                                             const float* __restrict__ Dp,
                                             const u16* __restrict__ xzbf,
                                             const float* __restrict__ Hinit,
                                             u16* __restrict__ ybf) {
  int d = blockIdx.x * 256 + threadIdx.x;
  int b = blockIdx.y, c = blockIdx.z;
  size_t row0 = (size_t)b * LSEQ + c * 64;
  float An[16];
  bool fast = true;
  {
    const float4* A4 = (const float4*)(A_log + (size_t)d * 16);
#pragma unroll
    for (int q = 0; q < 4; ++q) {
      float4 a = A4[q];
      An[q * 4 + 0] = -__expf(a.x);
      An[q * 4 + 1] = -__expf(a.y);
      An[q * 4 + 2] = -__expf(a.z);
      An[q * 4 + 3] = -__expf(a.w);
    }
#pragma unroll
    for (int n = 0; n < 16; ++n)
      fast = fast && (__builtin_fabsf(An[n] + (float)(n + 1)) < 1e-3f * (n + 1));
  }
  const u16* dtp = dtbf + row0 * DINNER + d;
  const u16* up = ubf + row0 * DINNER + d;
  const float* Bp = xdbl + row0 * 128 + 64;
  const float* Cp = xdbl + row0 * 128 + 80;
  const u16* gp = xzbf + row0 * 4096 + DINNER + d;  // silu(z), precomputed in GEMM1
  u16* yp = ybf + row0 * DINNER + d;
  float Dv = Dp[d];
  float h[16];
  {
    const float4* Hi4 = (const float4*)(Hinit + (size_t)c * 65536 + ((size_t)b * DINNER + d) * 16);
#pragma unroll
    for (int q = 0; q < 4; ++q) {
      float4 hv = Hi4[q];
      h[q * 4 + 0] = hv.x; h[q * 4 + 1] = hv.y; h[q * 4 + 2] = hv.z; h[q * 4 + 3] = hv.w;
    }
  }
#pragma unroll 2
  for (int i = 0; i < 64; ++i) {
    float dt = bf2f(dtp[(size_t)i * DINNER]);
    float uu = bf2f(up[(size_t)i * DINNER]);
    float dtu = dt * uu;
    const float4* B4 = (const float4*)(Bp + (size_t)i * 128);
    float4 b0 = B4[0], b1 = B4[1], b2 = B4[2], b3 = B4[3];
    float Bf[16] = {b0.x, b0.y, b0.z, b0.w, b1.x, b1.y, b1.z, b1.w,
                    b2.x, b2.y, b2.z, b2.w, b3.x, b3.y, b3.z, b3.w};
    const float4* C4 = (const float4*)(Cp + (size_t)i * 128);
    float4 c0 = C4[0], c1 = C4[1], c2 = C4[2], c3 = C4[3];
    float Cf[16] = {c0.x, c0.y, c0.z, c0.w, c1.x, c1.y, c1.z, c1.w,
                    c2.x, c2.y, c2.z, c2.w, c3.x, c3.y, c3.z, c3.w};
    float av[16];
    compute_a(dt, An, fast, av);
    float y = 0.f;
#pragma unroll
    for (int n = 0; n < 16; ++n) {
      h[n] = av[n] * h[n] + dtu * Bf[n];
      y += h[n] * Cf[n];
    }
    float g = bf2f(gp[(size_t)i * 4096]);
    yp[(size_t)i * DINNER] = f2bf((y + uu * Dv) * g);
  }
}

extern "C" void kernel_launch(void* const* d_in, const int* in_sizes, int n_in,
                              void* d_out, int out_size, void* d_ws, size_t ws_size,
                              hipStream_t stream) {
  const float* x = (const float*)d_in[0];
  const float* nw = (const float*)d_in[1];
  const float* nb = (const float*)d_in[2];
  const float* W_in = (const float*)d_in[3];
  const float* convw = (const float*)d_in[4];
  const float* convb = (const float*)d_in[5];
  const float* W_x = (const float*)d_in[6];
  const float* W_dt = (const float*)d_in[7];
  const float* b_dt = (const float*)d_in[8];
  const float* A_log = (const float*)d_in[9];
  const float* Dp = (const float*)d_in[10];
  const float* W_out = (const float*)d_in[11];
  float* out = (float*)d_out;

  char* wp = (char*)d_ws;
  auto alloc = [&](size_t bytes) {
    char* p = wp;
    wp += (bytes + 255) & ~(size_t)255;
    return p;
  };
  u16* xz_bf = (u16*)alloc((size_t)8192 * 4096 * 2);     // x half raw, z half silu'd
  u16* xconv_bf = (u16*)alloc((size_t)8192 * 2048 * 2);  // u
  u16* xn_bf = (u16*)alloc((size_t)8192 * 1024 * 2);
  float* xdbl = (float*)alloc((size_t)8192 * 128 * 4);
  u16* dt_bf = (u16*)alloc((size_t)8192 * 2048 * 2);     // softplus'd dt
  u16* dtlow_bf = (u16*)alloc((size_t)8192 * 64 * 2);
  u16* Wint = (u16*)alloc((size_t)4096 * 1024 * 2);
  u16* Wxt = (u16*)alloc((size_t)128 * 2048 * 2);
  u16* Wdtt = (u16*)alloc((size_t)2048 * 64 * 2);
  u16* Woutt = (u16*)alloc((size_t)1024 * 2048 * 2);
  float* P = (float*)alloc((size_t)64 * 65536 * 4);
  float* H = (float*)alloc((size_t)64 * 65536 * 4);
  float* Hinit = (float*)alloc((size_t)64 * 65536 * 4);
  // overlays on P∪H (16.8+16.8 MB):
  float* xdbl_part = (float*)P;  // 8*8192*128*4 = 33.5 MB; dead before scan1 writes P/H
  u16* y_bf = (u16*)P;           // 33.5 MB; written in scan3 (P/H dead after scan2)

  // weight prep (B^T bf16)
  tc_kernel<<<dim3(128, 32), 256, 0, stream>>>(W_in, Wint, 1024, 4096, 4096);
  tc_kernel<<<dim3(4, 64), 256, 0, stream>>>(W_x, Wxt, 2048, 96, 128);
  tc_kernel<<<dim3(64, 2), 256, 0, stream>>>(W_dt, Wdtt, 64, 2048, 2048);
  tc_kernel<<<dim3(32, 64), 256, 0, stream>>>(W_out, Woutt, 2048, 1024, 1024);

  ln_kernel<<<8192, 256, 0, stream>>>(x, nw, nb, xn_bf);
  // xz = xn @ W_in, z-half gets silu applied in epilogue
  gemm_bt<1, 2, 0><<<dim3(32, 64), 256, 0, stream>>>(xn_bf, Wint, xz_bf, nullptr,
                                                     8192, 4096, 1024, 1024, 2048);
  conv_silu<<<dim3(8, 512, 2), 256, 0, stream>>>(xz_bf, convw, convb, xconv_bf);
  // x_dbl = x_conv @ W_x : split-K x8 partials, then reduce (+ dt_low bf16 side-write)
  gemm_bt<0, 0, 1><<<dim3(1, 64, 8), 256, 0, stream>>>(xconv_bf, Wxt, xdbl_part, nullptr,
                                                       8192, 128, 256, 2048, 0);
  reduce_xdbl<<<4096, 256, 0, stream>>>(xdbl_part, xdbl, dtlow_bf);
  // dt = softplus(dt_low @ W_dt + b_dt)
  gemm_bt<1, 3, 0><<<dim3(16, 64), 256, 0, stream>>>(dtlow_bf, Wdtt, dt_bf, b_dt,
                                                     8192, 2048, 64, 64, 0);
  scan1<<<dim3(8, 2, 64), 256, 0, stream>>>(dt_bf, xconv_bf, xdbl, A_log, P, H);
  scan2<<<256, 256, 0, stream>>>(P, H, Hinit);
  scan3<<<dim3(8, 2, 64), 256, 0, stream>>>(dt_bf, xconv_bf, xdbl, A_log, Dp, xz_bf,
                                            Hinit, y_bf);
  // out = residual + y @ W_out
  gemm_bt<0, 1, 0><<<dim3(8, 64), 256, 0, stream>>>(y_bf, Woutt, out, x,
                                                    8192, 1024, 2048, 2048, 0);
}

// Round 4
// 346.441 us; speedup vs baseline: 2.6826x; 1.0469x over previous
//
#include <hip/hip_runtime.h>

typedef unsigned short u16;
typedef __attribute__((ext_vector_type(8))) __bf16 bf16x8;
typedef __attribute__((ext_vector_type(4))) float f32x4;

#define LSEQ 4096
#define DMODEL 1024
#define DINNER 2048

__device__ __forceinline__ float bf2f(u16 u) {
  union { unsigned u; float f; } v; v.u = ((unsigned)u) << 16; return v.f;
}
__device__ __forceinline__ u16 f2bf(float f) {
  union { float f; unsigned u; } v; v.f = f;
  unsigned r = v.u + 0x7fffu + ((v.u >> 16) & 1u);
  return (u16)(r >> 16);
}
__device__ __forceinline__ void gload_lds16(const void* g, void* l) {
  __builtin_amdgcn_global_load_lds(
      (__attribute__((address_space(1))) void*)(unsigned long long)g,
      (__attribute__((address_space(3))) void*)(unsigned int)(unsigned long long)l,
      16, 0, 0);
}
__device__ __forceinline__ float sigmoidf_(float v) { return 1.f / (1.f + __expf(-v)); }

// ---------------- LayerNorm -> bf16 ----------------
__global__ __launch_bounds__(256) void ln_kernel(const float* __restrict__ x,
                                                 const float* __restrict__ w,
                                                 const float* __restrict__ b,
                                                 u16* __restrict__ out) {
  int row = blockIdx.x;
  const float* xr = x + (size_t)row * DMODEL;
  int t = threadIdx.x;
  float4 v = ((const float4*)xr)[t];
  float s = v.x + v.y + v.z + v.w;
  float s2 = v.x * v.x + v.y * v.y + v.z * v.z + v.w * v.w;
  for (int off = 32; off; off >>= 1) {
    s += __shfl_down(s, off);
    s2 += __shfl_down(s2, off);
  }
  __shared__ float ls[4], ls2[4];
  int wid = t >> 6;
  if ((t & 63) == 0) { ls[wid] = s; ls2[wid] = s2; }
  __syncthreads();
  s = ls[0] + ls[1] + ls[2] + ls[3];
  s2 = ls2[0] + ls2[1] + ls2[2] + ls2[3];
  float mu = s * (1.f / DMODEL);
  float var = s2 * (1.f / DMODEL) - mu * mu;
  float rs = rsqrtf(var + 1e-5f);
  float4 wv = ((const float4*)w)[t];
  float4 bv = ((const float4*)b)[t];
  unsigned p0 = (unsigned)f2bf((v.x - mu) * rs * wv.x + bv.x) |
                ((unsigned)f2bf((v.y - mu) * rs * wv.y + bv.y) << 16);
  unsigned p1 = (unsigned)f2bf((v.z - mu) * rs * wv.z + bv.z) |
                ((unsigned)f2bf((v.w - mu) * rs * wv.w + bv.w) << 16);
  ((uint2*)(out + (size_t)row * DMODEL))[t] = make_uint2(p0, p1);
}

// ---------------- transpose + cast f32[K][N] -> bf16[Npad][K], zero-fill ----------------
__global__ __launch_bounds__(256) void tc_kernel(const float* __restrict__ in,
                                                 u16* __restrict__ out,
                                                 int K, int N, int Npad) {
  __shared__ float tile[32][33];
  int n0 = blockIdx.x * 32, k0 = blockIdx.y * 32;
  int tx = threadIdx.x & 31, ty = threadIdx.x >> 5;
  for (int i = ty; i < 32; i += 8) {
    int k = k0 + i, n = n0 + tx;
    tile[i][tx] = (k < K && n < N) ? in[(size_t)k * N + n] : 0.f;
  }
  __syncthreads();
  for (int i = ty; i < 32; i += 8) {
    int n = n0 + i, k = k0 + tx;
    if (n < Npad && k < K) out[(size_t)n * K + k] = f2bf(tile[tx][i]);
  }
}

// =====================================================================================
// 256x256 8-phase GEMM (T2 swizzle + T3/T4 counted vmcnt + T5 setprio)
// C[M][N] = A[M][K] * Bt[N][K]^T. Requires M%256==0, N%256==0, K%64==0, K/64>=2.
// LDS: A,B each [2 bufs][256 rows][64 k] bf16, 16B k-slots XOR-swizzled by (row&7).
// Staged linearly by global_load_lds with inverse-swizzled per-lane GLOBAL source.
// Schedule per K-tile T (buf b0=T&1): 4 phases = C-quadrants (mh,nh) in order
// (0,0),(0,1),(1,1),(1,0); phase p stages one 16KB unit: p0: A-hi(T+1)->b1,
// p1: A-lo(T+2)->b0, p2: B-lo(T+2)->b0, p3: B-hi(T+2)->b0 (targets proven freed).
// One s_waitcnt vmcnt(6) per K-tile at p3 (3 half-tiles = 6 loads in flight).
// =====================================================================================
__device__ __forceinline__ void stage8(const u16* grow0, int ld, int kcol0,
                                       u16* lds_u, int ln) {
  int rr = ln >> 3, kb = ln & 7;  // 8 rows x 8 16B-slots; logical slot = phys ^ row
  gload_lds16(grow0 + (size_t)rr * ld + kcol0 + ((kb ^ rr) << 3), lds_u);
}

#define LDA_FRAGS(mh, buf)                                                         \
  _Pragma("unroll") for (int mf = 0; mf < 4; ++mf)                                 \
  _Pragma("unroll") for (int kk = 0; kk < 2; ++kk)                                 \
    a[mf][kk] = *(const bf16x8*)(LA + (buf) * 16384 +                              \
        (wm * 128 + (mh) * 64 + mf * 16 + lr) * 64 + (((kk * 4 + lq) ^ key) << 3));

#define LDB_FRAGS(nh, buf)                                                         \
  _Pragma("unroll") for (int nf = 0; nf < 2; ++nf)                                 \
  _Pragma("unroll") for (int kk = 0; kk < 2; ++kk)                                 \
    bb[nh][nf][kk] = *(const bf16x8*)(LB + (buf) * 16384 +                         \
        (wn * 64 + (nh) * 32 + nf * 16 + lr) * 64 + (((kk * 4 + lq) ^ key) << 3));

#define MFMA_Q(mh, nh)                                                             \
  __builtin_amdgcn_s_setprio(1);                                                   \
  _Pragma("unroll") for (int mf = 0; mf < 4; ++mf)                                 \
  _Pragma("unroll") for (int nf = 0; nf < 2; ++nf)                                 \
  _Pragma("unroll") for (int kk = 0; kk < 2; ++kk)                                 \
    acc[(mh) * 4 + mf][(nh) * 2 + nf] = __builtin_amdgcn_mfma_f32_16x16x32_bf16(   \
        a[mf][kk], bb[nh][nf][kk], acc[(mh) * 4 + mf][(nh) * 2 + nf], 0, 0, 0);    \
  __builtin_amdgcn_s_setprio(0);

#define STAGE_A(unit, kt, buf)                                                     \
  _Pragma("unroll") for (int c = 0; c < 2; ++c) {                                  \
    int g = w * 2 + c;                                                             \
    int r0 = ((g < 8) ? g * 8 : (g - 8) * 8 + 128) + (unit) * 64;                  \
    stage8(Ag + (size_t)r0 * K, K, (kt) * 64, LA + (buf) * 16384 + r0 * 64, ln);   \
  }

#define STAGE_B(half, kt, buf)                                                     \
  _Pragma("unroll") for (int c = 0; c < 2; ++c) {                                  \
    int g = w * 2 + c;                                                             \
    int r0 = (g >> 2) * 64 + (half) * 32 + (g & 3) * 8;                            \
    stage8(Bg + (size_t)r0 * K, K, (kt) * 64, LB + (buf) * 16384 + r0 * 64, ln);   \
  }

template <int OUT_BF16, int EPI>  // EPI: 1 = +aux residual (f32), 2 = silu col>=cthresh
__global__ __launch_bounds__(512, 2) void gemm8p(const u16* __restrict__ A,
                                                 const u16* __restrict__ Bt,
                                                 void* __restrict__ Cout,
                                                 const float* __restrict__ aux,
                                                 int M, int N, int K, int cthresh) {
  __shared__ alignas(16) u16 lds[65536];
  u16* LA = lds;
  u16* LB = lds + 32768;
  int t = threadIdx.x;
  int w = t >> 6, ln = t & 63;
  int wm = w >> 2, wn = w & 3;
  int bm = blockIdx.y, bn = blockIdx.x;
  int lr = ln & 15, lq = ln >> 4, key = ln & 7;
  int NT = K >> 6;
  const u16* Ag = A + (size_t)bm * 256 * K;
  const u16* Bg = Bt + (size_t)bn * 256 * K;
  f32x4 acc[8][4] = {};
  bf16x8 a[4][2], bb[2][2][2];

  // prologue: K-tile 0 (all 4 units) then K-tile 1 (U0, B-lo, B-hi); A-hi(1) comes at p0.
  STAGE_A(0, 0, 0); STAGE_B(0, 0, 0); STAGE_B(1, 0, 0); STAGE_A(1, 0, 0);
  int k1 = NT > 1 ? 1 : 0;
  STAGE_A(0, k1, 1); STAGE_B(0, k1, 1); STAGE_B(1, k1, 1);
  asm volatile("s_waitcnt vmcnt(6)" ::: "memory");
  __builtin_amdgcn_s_barrier();

  for (int T = 0; T < NT; ++T) {
    int b0 = T & 1, b1 = b0 ^ 1;
    int kt1 = (T + 1 < NT) ? T + 1 : NT - 1;
    int kt2 = (T + 2 < NT) ? T + 2 : NT - 1;
    // P0: quadrant (m-lo, n-lo)
    LDA_FRAGS(0, b0);
    LDB_FRAGS(0, b0);
    STAGE_A(1, kt1, b1);
    __builtin_amdgcn_s_barrier();
    asm volatile("s_waitcnt lgkmcnt(0)" ::: "memory");
    MFMA_Q(0, 0);
    __builtin_amdgcn_s_barrier();
    // P1: (m-lo, n-hi)
    LDB_FRAGS(1, b0);
    STAGE_A(0, kt2, b0);
    __builtin_amdgcn_s_barrier();
    asm volatile("s_waitcnt lgkmcnt(0)" ::: "memory");
    MFMA_Q(0, 1);
    __builtin_amdgcn_s_barrier();
    // P2: (m-hi, n-hi)
    LDA_FRAGS(1, b0);
    STAGE_B(0, kt2, b0);
    __builtin_amdgcn_s_barrier();
    asm volatile("s_waitcnt lgkmcnt(0)" ::: "memory");
    MFMA_Q(1, 1);
    __builtin_amdgcn_s_barrier();
    // P3: (m-hi, n-lo); K-tile boundary wait
    STAGE_B(1, kt2, b0);
    asm volatile("s_waitcnt vmcnt(6)" ::: "memory");
    __builtin_amdgcn_s_barrier();
    MFMA_Q(1, 0);
    __builtin_amdgcn_s_barrier();
  }

  int crow0 = bm * 256 + wm * 128;
  int ccol0 = bn * 256 + wn * 64;
#pragma unroll
  for (int mf = 0; mf < 8; ++mf)
#pragma unroll
    for (int nf = 0; nf < 4; ++nf)
#pragma unroll
      for (int r = 0; r < 4; ++r) {
        int row = crow0 + mf * 16 + lq * 4 + r;
        int col = ccol0 + nf * 16 + lr;
        float v = acc[mf][nf][r];
        if (EPI == 1) v += aux[(size_t)row * N + col];
        if (EPI == 2 && col >= cthresh) v = v * sigmoidf_(v);
        if (OUT_BF16)
          ((u16*)Cout)[(size_t)row * N + col] = f2bf(v);
        else
          ((float*)Cout)[(size_t)row * N + col] = v;
      }
}

// ---------------- 128x128 bf16 GEMM (kept for small/odd shapes) ----------------
// EPI: 0 none, 3 softplus(v + aux[col]); SPLITK: partials at z*M*N
template <int OUT_BF16, int EPI, int SPLITK>
__global__ __launch_bounds__(256) void gemm_bt(const u16* __restrict__ A,
                                               const u16* __restrict__ Bt,
                                               void* __restrict__ Cout,
                                               const float* __restrict__ aux,
                                               int M, int N, int K, int ld, int cthresh) {
  __shared__ alignas(16) u16 As[128 * 32];
  __shared__ alignas(16) u16 Bs[128 * 32];
  int t = threadIdx.x;
  int w = t >> 6, ln = t & 63;
  int wr = w >> 1, wc = w & 1;
  int bm = blockIdx.y, bn = blockIdx.x;
  int lr = ln & 15, lk = (ln >> 4) * 8;
  f32x4 acc[4][4] = {};
  int kz = SPLITK ? blockIdx.z * K : 0;
  const u16* Abase = A + (size_t)bm * 128 * ld + kz;
  const u16* Bbase = Bt + (size_t)bn * 128 * ld + kz;
  for (int k0 = 0; k0 < K; k0 += 32) {
#pragma unroll
    for (int c = 0; c < 2; ++c) {
      int chunk = w * 2 + c;
      int ee = chunk * 512 + ln * 8;
      int row = ee >> 5, col = ee & 31;
      gload_lds16(Abase + (size_t)row * ld + k0 + col, As + chunk * 512);
      gload_lds16(Bbase + (size_t)row * ld + k0 + col, Bs + chunk * 512);
    }
    __syncthreads();
    bf16x8 af[4], bfr[4];
#pragma unroll
    for (int m = 0; m < 4; ++m)
      af[m] = *(const bf16x8*)(As + (wr * 64 + m * 16 + lr) * 32 + lk);
#pragma unroll
    for (int n = 0; n < 4; ++n)
      bfr[n] = *(const bf16x8*)(Bs + (wc * 64 + n * 16 + lr) * 32 + lk);
#pragma unroll
    for (int m = 0; m < 4; ++m)
#pragma unroll
      for (int n = 0; n < 4; ++n)
        acc[m][n] = __builtin_amdgcn_mfma_f32_16x16x32_bf16(af[m], bfr[n], acc[m][n], 0, 0, 0);
    __syncthreads();
  }
  int rb = bm * 128 + wr * 64 + (ln >> 4) * 4;
  int cb = bn * 128 + wc * 64 + lr;
  float* Cpart = SPLITK ? ((float*)Cout + (size_t)blockIdx.z * M * N) : (float*)Cout;
#pragma unroll
  for (int m = 0; m < 4; ++m)
#pragma unroll
    for (int n = 0; n < 4; ++n)
#pragma unroll
      for (int r = 0; r < 4; ++r) {
        int row = rb + m * 16 + r;
        int col = cb + n * 16;
        float v = acc[m][n][r];
        if (EPI == 3) {
          float dtr = v + aux[col];
          v = dtr > 15.f ? dtr : __logf(1.f + __expf(dtr));
        }
        if (OUT_BF16)
          ((u16*)Cpart)[(size_t)row * N + col] = f2bf(v);
        else
          Cpart[(size_t)row * N + col] = v;
      }
}

// ---------------- reduce split-K partials -> xdbl f32, side-write dt_low bf16 ----------------
__global__ __launch_bounds__(256) void reduce_xdbl(const float* __restrict__ part,
                                                   float* __restrict__ xdbl,
                                                   u16* __restrict__ dtlow) {
  int i = blockIdx.x * 256 + threadIdx.x;  // over 8192*128
  float s = 0.f;
#pragma unroll
  for (int z = 0; z < 8; ++z) s += part[(size_t)z * (8192 * 128) + i];
  xdbl[i] = s;
  int col = i & 127;
  if (col < 64) dtlow[(size_t)(i >> 7) * 64 + col] = f2bf(s);
}

// ---------------- depthwise causal conv(4) + SiLU ----------------
__global__ __launch_bounds__(256) void conv_silu(const u16* __restrict__ xz,
                                                 const float* __restrict__ cw,
                                                 const float* __restrict__ cb,
                                                 u16* __restrict__ out) {
  int d = blockIdx.x * 256 + threadIdx.x;
  int l0 = blockIdx.y * 8;
  int b = blockIdx.z;
  float w0 = cw[d * 4 + 0], w1 = cw[d * 4 + 1], w2 = cw[d * 4 + 2], w3 = cw[d * 4 + 3];
  float bias = cb[d];
  const u16* xp = xz + ((size_t)b * LSEQ) * 4096 + d;
  float xv[11];
#pragma unroll
  for (int i = 0; i < 11; ++i) {
    int l = l0 - 3 + i;
    xv[i] = (l >= 0) ? bf2f(xp[(size_t)l * 4096]) : 0.f;
  }
  u16* op = out + ((size_t)b * LSEQ + l0) * DINNER + d;
#pragma unroll
  for (int i = 0; i < 8; ++i) {
    float acc = bias + w0 * xv[i] + w1 * xv[i + 1] + w2 * xv[i + 2] + w3 * xv[i + 3];
    float sv = acc * sigmoidf_(acc);
    op[(size_t)i * DINNER] = f2bf(sv);
  }
}

// ---- compute a[16] = exp(dt*An[n]); fast path when An = -(n+1) (uniform branch) ----
__device__ __forceinline__ void compute_a(float dt, const float* An, bool fast, float* av) {
  if (fast) {
    float q = __expf(-dt);
    float q2 = q * q, q4 = q2 * q2;
    av[0] = q; av[1] = q2; av[2] = q2 * q; av[3] = q4;
#pragma unroll
    for (int n = 4; n < 16; ++n) av[n] = av[n - 4] * q4;
  } else {
#pragma unroll
    for (int n = 0; n < 16; ++n) av[n] = __expf(dt * An[n]);
  }
}

// ---------------- scan pass 1: per-chunk local scan; 1 lane = 1 channel ----------------
__global__ __launch_bounds__(256) void scan1(const u16* __restrict__ dtbf,
                                             const u16* __restrict__ ubf,
                                             const float* __restrict__ xdbl,
                                             const float* __restrict__ A_log,
                                             float* __restrict__ P,
                                             float* __restrict__ H) {
  int d = blockIdx.x * 256 + threadIdx.x;
  int b = blockIdx.y, c = blockIdx.z;
  size_t row0 = (size_t)b * LSEQ + c * 64;
  float An[16];
  bool fast = true;
  {
    const float4* A4 = (const float4*)(A_log + (size_t)d * 16);
#pragma unroll
    for (int q = 0; q < 4; ++q) {
      float4 a = A4[q];
      An[q * 4 + 0] = -__expf(a.x);
      An[q * 4 + 1] = -__expf(a.y);
      An[q * 4 + 2] = -__expf(a.z);
      An[q * 4 + 3] = -__expf(a.w);
    }
#pragma unroll
    for (int n = 0; n < 16; ++n)
      fast = fast && (__builtin_fabsf(An[n] + (float)(n + 1)) < 1e-3f * (n + 1));
  }
  const u16* dtp = dtbf + row0 * DINNER + d;
  const u16* up = ubf + row0 * DINNER + d;
  const float* Bp = xdbl + row0 * 128 + 64;
  float h[16];
#pragma unroll
  for (int n = 0; n < 16; ++n) h[n] = 0.f;
  float sdt = 0.f;
#pragma unroll 2
  for (int i = 0; i < 64; ++i) {
    float dt = bf2f(dtp[(size_t)i * DINNER]);
    float uu = bf2f(up[(size_t)i * DINNER]);
    float dtu = dt * uu;
    sdt += dt;
    const float4* B4 = (const float4*)(Bp + (size_t)i * 128);
    float4 b0 = B4[0], b1 = B4[1], b2 = B4[2], b3 = B4[3];
    float Bf[16] = {b0.x, b0.y, b0.z, b0.w, b1.x, b1.y, b1.z, b1.w,
                    b2.x, b2.y, b2.z, b2.w, b3.x, b3.y, b3.z, b3.w};
    float av[16];
    compute_a(dt, An, fast, av);
#pragma unroll
    for (int n = 0; n < 16; ++n) h[n] = av[n] * h[n] + dtu * Bf[n];
  }
  size_t idx = (size_t)c * 65536 + ((size_t)b * DINNER + d) * 16;
  float4* P4 = (float4*)(P + idx);
  float4* H4 = (float4*)(H + idx);
#pragma unroll
  for (int q = 0; q < 4; ++q) {
    P4[q] = make_float4(__expf(An[q * 4 + 0] * sdt), __expf(An[q * 4 + 1] * sdt),
                        __expf(An[q * 4 + 2] * sdt), __expf(An[q * 4 + 3] * sdt));
    H4[q] = make_float4(h[q * 4], h[q * 4 + 1], h[q * 4 + 2], h[q * 4 + 3]);
  }
}

// ---------------- scan pass 2: combine chunks ----------------
__global__ __launch_bounds__(256) void scan2(const float* __restrict__ P,
                                             const float* __restrict__ H,
                                             float* __restrict__ Hinit) {
  int i = blockIdx.x * 256 + threadIdx.x;
  float h = 0.f;
  for (int c = 0; c < 64; ++c) {
    Hinit[(size_t)c * 65536 + i] = h;
    h = P[(size_t)c * 65536 + i] * h + H[(size_t)c * 65536 + i];
  }
}

// ---------------- scan pass 3: replay with true h_init; fused D-term + precomputed gate ----
__global__ __launch_bounds__(256) void scan3(const u16* __restrict__ dtbf,
                                             const u16* __restrict__ ubf,
                                             const float* __restrict__ xdbl,
                                             const float* __restrict__ A_log,
                                             const float* __restrict__ Dp,
                                             const u16* __restrict__ xzbf,
                                             const float* __restrict__ Hinit,
                                             u16* __restrict__ ybf) {
  int d = blockIdx.x * 256 + threadIdx.x;
  int b = blockIdx.y, c = blockIdx.z;
  size_t row0 = (size_t)b * LSEQ + c * 64;
  float An[16];
  bool fast = true;
  {
    const float4* A4 = (const float4*)(A_log + (size_t)d * 16);
#pragma unroll
    for (int q = 0; q < 4; ++q) {
      float4 a = A4[q];
      An[q * 4 + 0] = -__expf(a.x);
      An[q * 4 + 1] = -__expf(a.y);
      An[q * 4 + 2] = -__expf(a.z);
      An[q * 4 + 3] = -__expf(a.w);
    }
#pragma unroll
    for (int n = 0; n < 16; ++n)
      fast = fast && (__builtin_fabsf(An[n] + (float)(n + 1)) < 1e-3f * (n + 1));
  }
  const u16* dtp = dtbf + row0 * DINNER + d;
  const u16* up = ubf + row0 * DINNER + d;
  const float* Bp = xdbl + row0 * 128 + 64;
  const float* Cp = xdbl + row0 * 128 + 80;
  const u16* gp = xzbf + row0 * 4096 + DINNER + d;
  u16* yp = ybf + row0 * DINNER + d;
  float Dv = Dp[d];
  float h[16];
  {
    const float4* Hi4 = (const float4*)(Hinit + (size_t)c * 65536 + ((size_t)b * DINNER + d) * 16);
#pragma unroll
    for (int q = 0; q < 4; ++q) {
      float4 hv = Hi4[q];
      h[q * 4 + 0] = hv.x; h[q * 4 + 1] = hv.y; h[q * 4 + 2] = hv.z; h[q * 4 + 3] = hv.w;
    }
  }
#pragma unroll 2
  for (int i = 0; i < 64; ++i) {
    float dt = bf2f(dtp[(size_t)i * DINNER]);
    float uu = bf2f(up[(size_t)i * DINNER]);
    float dtu = dt * uu;
    const float4* B4 = (const float4*)(Bp + (size_t)i * 128);
    float4 b0 = B4[0], b1 = B4[1], b2 = B4[2], b3 = B4[3];
    float Bf[16] = {b0.x, b0.y, b0.z, b0.w, b1.x, b1.y, b1.z, b1.w,
                    b2.x, b2.y, b2.z, b2.w, b3.x, b3.y, b3.z, b3.w};
    const float4* C4 = (const float4*)(Cp + (size_t)i * 128);
    float4 c0 = C4[0], c1 = C4[1], c2 = C4[2], c3 = C4[3];
    float Cf[16] = {c0.x, c0.y, c0.z, c0.w, c1.x, c1.y, c1.z, c1.w,
                    c2.x, c2.y, c2.z, c2.w, c3.x, c3.y, c3.z, c3.w};
    float av[16];
    compute_a(dt, An, fast, av);
    float y = 0.f;
#pragma unroll
    for (int n = 0; n < 16; ++n) {
      h[n] = av[n] * h[n] + dtu * Bf[n];
      y += h[n] * Cf[n];
    }
    float g = bf2f(gp[(size_t)i * 4096]);
    yp[(size_t)i * DINNER] = f2bf((y + uu * Dv) * g);
  }
}

extern "C" void kernel_launch(void* const* d_in, const int* in_sizes, int n_in,
                              void* d_out, int out_size, void* d_ws, size_t ws_size,
                              hipStream_t stream) {
  const float* x = (const float*)d_in[0];
  const float* nw = (const float*)d_in[1];
  const float* nb = (const float*)d_in[2];
  const float* W_in = (const float*)d_in[3];
  const float* convw = (const float*)d_in[4];
  const float* convb = (const float*)d_in[5];
  const float* W_x = (const float*)d_in[6];
  const float* W_dt = (const float*)d_in[7];
  const float* b_dt = (const float*)d_in[8];
  const float* A_log = (const float*)d_in[9];
  const float* Dp = (const float*)d_in[10];
  const float* W_out = (const float*)d_in[11];
  float* out = (float*)d_out;

  char* wp = (char*)d_ws;
  auto alloc = [&](size_t bytes) {
    char* p = wp;
    wp += (bytes + 255) & ~(size_t)255;
    return p;
  };
  u16* xz_bf = (u16*)alloc((size_t)8192 * 4096 * 2);     // x half raw, z half silu'd
  u16* xconv_bf = (u16*)alloc((size_t)8192 * 2048 * 2);  // u
  u16* xn_bf = (u16*)alloc((size_t)8192 * 1024 * 2);
  float* xdbl = (float*)alloc((size_t)8192 * 128 * 4);
  u16* dt_bf = (u16*)alloc((size_t)8192 * 2048 * 2);     // softplus'd dt
  u16* dtlow_bf = (u16*)alloc((size_t)8192 * 64 * 2);
  u16* Wint = (u16*)alloc((size_t)4096 * 1024 * 2);
  u16* Wxt = (u16*)alloc((size_t)128 * 2048 * 2);
  u16* Wdtt = (u16*)alloc((size_t)2048 * 64 * 2);
  u16* Woutt = (u16*)alloc((size_t)1024 * 2048 * 2);
  float* P = (float*)alloc((size_t)64 * 65536 * 4);
  float* H = (float*)alloc((size_t)64 * 65536 * 4);
  float* Hinit = (float*)alloc((size_t)64 * 65536 * 4);
  // overlays on P∪H:
  float* xdbl_part = (float*)P;  // split-K partials, dead before scan1
  u16* y_bf = (u16*)P;           // scan3 output, P/H dead after scan2

  // weight prep (B^T bf16)
  tc_kernel<<<dim3(128, 32), 256, 0, stream>>>(W_in, Wint, 1024, 4096, 4096);
  tc_kernel<<<dim3(4, 64), 256, 0, stream>>>(W_x, Wxt, 2048, 96, 128);
  tc_kernel<<<dim3(64, 2), 256, 0, stream>>>(W_dt, Wdtt, 64, 2048, 2048);
  tc_kernel<<<dim3(32, 64), 256, 0, stream>>>(W_out, Woutt, 2048, 1024, 1024);

  ln_kernel<<<8192, 256, 0, stream>>>(x, nw, nb, xn_bf);
  // xz = xn @ W_in, z-half silu'd in epilogue  (8-phase 256^2)
  gemm8p<1, 2><<<dim3(16, 32), 512, 0, stream>>>(xn_bf, Wint, xz_bf, nullptr,
                                                 8192, 4096, 1024, 2048);
  conv_silu<<<dim3(8, 512, 2), 256, 0, stream>>>(xz_bf, convw, convb, xconv_bf);
  // x_dbl = x_conv @ W_x : split-K x8 partials, then reduce (+ dt_low bf16 side-write)
  gemm_bt<0, 0, 1><<<dim3(1, 64, 8), 256, 0, stream>>>(xconv_bf, Wxt, xdbl_part, nullptr,
                                                       8192, 128, 256, 2048, 0);
  reduce_xdbl<<<4096, 256, 0, stream>>>(xdbl_part, xdbl, dtlow_bf);
  // dt = softplus(dt_low @ W_dt + b_dt)
  gemm_bt<1, 3, 0><<<dim3(16, 64), 256, 0, stream>>>(dtlow_bf, Wdtt, dt_bf, b_dt,
                                                     8192, 2048, 64, 64, 0);
  scan1<<<dim3(8, 2, 64), 256, 0, stream>>>(dt_bf, xconv_bf, xdbl, A_log, P, H);
  scan2<<<256, 256, 0, stream>>>(P, H, Hinit);
  scan3<<<dim3(8, 2, 64), 256, 0, stream>>>(dt_bf, xconv_bf, xdbl, A_log, Dp, xz_bf,
                                            Hinit, y_bf);
  // out = residual + y @ W_out  (8-phase 256^2)
  gemm8p<0, 1><<<dim3(4, 32), 512, 0, stream>>>(y_bf, Woutt, out, x,
                                                8192, 1024, 2048, 0);
}